// Round 9
// baseline (369.062 us; speedup 1.0000x reference)
//
#include <hip/hip_runtime.h>
#include <math.h>

#define N_NODES 50000
#define N_EDGES 800000
#define NGRAPHS 256
#define NCONV 3
#define DMAX 64      // padded CSR row stride; max in-degree+1 (Binomial mean 16) << 64
#define ROW_BLKS 782 // divup(N_NODES, 64)
#define GEMM_BLOCKS 1564  // ROW_BLKS * 2 col-slices (64 cols each)
#define SCHUNK 2048       // edges per scatter block (256 thr x 8 iters)
#define NCHUNKS 391       // divup(N_EDGES, SCHUNK)
#define HALF0 196         // chunks 0..195 ride feat-gemm; 196..390 ride conv0-gemm

typedef _Float16 h4 __attribute__((ext_vector_type(4)));
typedef _Float16 h8 __attribute__((ext_vector_type(8)));
typedef float f32x4 __attribute__((ext_vector_type(4)));

static inline int divup(int a, int b) { return (a + b - 1) / b; }

// SB layout (floats): double-buffered 8-sliced conv stats (CONV0/CONV1 — the
// in-gemm fold READS one buffer while early blocks ZERO the other; never same),
// feat stats X, head stats H2. Stats atomics only from low-contention configs
// (round-1 lesson: 3.2M atomics into 8KB = 200+ us wall; we stay ~200K into 8KB).
#define SB_CONV0 0
#define SB_CONV1 2048
#define SB_X 4096
#define SB_H2 4352
#define SB_TOT 4608

// ---------------- init: zero SB (BEFORE any stats accumulation), self-loops ----------------
__global__ void init_kernel(float* __restrict__ SB, int* __restrict__ cursor,
                            unsigned short* __restrict__ col, int n) {
    int i = blockIdx.x * blockDim.x + threadIdx.x;
    if (i < SB_TOT) SB[i] = 0.f;
    if (i < n) {
        cursor[i] = 1;              // slot 0 = self-loop
        col[(size_t)i * DMAX] = (unsigned short)i;
    }
}

// ---------------- cast f32->f16 + column stats ----------
__global__ __launch_bounds__(256) void cast_stats(const float* __restrict__ x,
                                                  _Float16* __restrict__ y, int n,
                                                  float* __restrict__ sums) {
    __shared__ float S[16][128], S2[16][128];
    int tid = threadIdx.x;
    int c8 = (tid & 15) * 8;
    int rg = tid >> 4;
    float s[8] = {}, s2[8] = {};
    for (int r = blockIdx.x * 16 + rg; r < n; r += gridDim.x * 16) {
        const float4* p = (const float4*)&x[(size_t)r * 128 + c8];
        float4 v0 = p[0], v1 = p[1];
        float f[8] = {v0.x, v0.y, v0.z, v0.w, v1.x, v1.y, v1.z, v1.w};
        h8 o;
#pragma unroll
        for (int i = 0; i < 8; ++i) {
            o[i] = (_Float16)f[i];
            s[i] += f[i];
            s2[i] += f[i] * f[i];
        }
        *(h8*)&y[(size_t)r * 128 + c8] = o;
    }
#pragma unroll
    for (int i = 0; i < 8; ++i) { S[rg][c8 + i] = s[i]; S2[rg][c8 + i] = s2[i]; }
    __syncthreads();
    if (tid < 128) {
        float a = 0.f, b = 0.f;
#pragma unroll
        for (int k = 0; k < 16; ++k) { a += S[k][tid]; b += S2[k][tid]; }
        atomicAdd(&sums[tid], a);
        atomicAdd(&sums[128 + tid], b);
    }
}

// ---------------- column stats, fp16 input (256 blocks -> slice 0..7 by blockIdx&7) ----------
__global__ __launch_bounds__(256) void colstats_h(const _Float16* __restrict__ x, int n,
                                                  float* __restrict__ sums) {
    __shared__ float S[16][128], S2[16][128];
    int tid = threadIdx.x;
    int c8 = (tid & 15) * 8;
    int rg = tid >> 4;
    float s[8] = {}, s2[8] = {};
    for (int r = blockIdx.x * 16 + rg; r < n; r += gridDim.x * 16) {
        h8 v = *(const h8*)&x[(size_t)r * 128 + c8];
#pragma unroll
        for (int i = 0; i < 8; ++i) {
            float f = (float)v[i];
            s[i] += f;
            s2[i] += f * f;
        }
    }
#pragma unroll
    for (int i = 0; i < 8; ++i) { S[rg][c8 + i] = s[i]; S2[rg][c8 + i] = s2[i]; }
    __syncthreads();
    if (tid < 128) {
        float a = 0.f, b = 0.f;
#pragma unroll
        for (int k = 0; k < 16; ++k) { a += S[k][tid]; b += S2[k][tid]; }
        atomicAdd(&sums[(blockIdx.x & 7) * 256 + tid], a);
        atomicAdd(&sums[(blockIdx.x & 7) * 256 + 128 + tid], b);
    }
}

// ---------------- MFMA fp16 GEMM, N-SPLIT for occupancy, with INLINE BN-fold --------------
// r8 PMC: gemm occupancy 31% — grid 391 blocks = 1.5/CU, machine 3/4 empty.
// Fix: 64 rows x 64 cols per 256-thr block -> grid 1564 = 6.1 blk/CU; Wl
// halves to 17.4KB (LDS ~20KB -> 7 blk/CU capacity) -> ~24 waves/CU (76%).
// A read 2x chip-wide (L2-absorbed). Col-block owns heads {0,1} or {2,3} —
// als/ald writes disjoint. Inline fold per col-slice (W L2-hot broadcast).
// Scatter tail blocks (blockIdx >= GEMM_BLOCKS) return pre-barrier.
// Feat-gemm stats epilogue: 128 atomics x 1564 blocks = 200K into 8 slices — safe.
__global__ __launch_bounds__(256) void gemm_mfma(const _Float16* __restrict__ Ah,
                                                 const float* __restrict__ W,
                                                 const float* __restrict__ gamma,
                                                 const float* __restrict__ beta,
                                                 const float* __restrict__ stats, int nsl,
                                                 float inv_n,
                                                 _Float16* __restrict__ outh, int n, int relu,
                                                 const float* __restrict__ asrc,
                                                 const float* __restrict__ adst,
                                                 float* __restrict__ als,
                                                 float* __restrict__ ald,
                                                 float* __restrict__ stats8,
                                                 float* __restrict__ sums_zero,
                                                 float* __restrict__ g_zero,
                                                 const int* __restrict__ s_src,
                                                 const int* __restrict__ s_dst,
                                                 int* __restrict__ s_cursor,
                                                 unsigned short* __restrict__ s_col,
                                                 int s_E, int s_chunk0) {
    __shared__ _Float16 Wl[64 * 136];
    __shared__ float Sl2[128];           // [0..63] col-sum, [64..127] col-sumsq
    __shared__ float scL[128], tL[128];  // BN scale / shift
    __shared__ float pbp[4][64];         // bp partials
    __shared__ float bpL[64];            // folded bias (this col-slice)
    int tid = threadIdx.x;
    if ((int)blockIdx.x >= GEMM_BLOCKS) {
        // ---- scatter tail: XCD-sliced padded-CSR edge scatter ----
        int sb = blockIdx.x - GEMM_BLOCKS;
        int slice = sb & 7;
        int chunk = s_chunk0 + (sb >> 3);
        int base = chunk * SCHUNK;
        int lim = min(base + SCHUNK, s_E);
        int lo = slice * (N_NODES / 8);
        int hi = lo + (N_NODES / 8);
        for (int i = base + tid; i < lim; i += 256) {
            int d = s_dst[i];
            if (d >= lo && d < hi) {
                int p = atomicAdd(&s_cursor[d], 1);
                if (p < DMAX) s_col[(size_t)d * DMAX + p] = (unsigned short)s_src[i];
            }
        }
        return;  // before any barrier
    }
    if (sums_zero && blockIdx.x < 8) sums_zero[blockIdx.x * 256 + tid] = 0.f;
    if (g_zero && blockIdx.x < 128) g_zero[blockIdx.x * 256 + tid] = 0.f;
    const bool do_st = (stats8 != nullptr);
    if (do_st && tid < 128) Sl2[tid] = 0.f;
    int row_blk = blockIdx.x >> 1;
    int colbase = (blockIdx.x & 1) << 6;   // 0 or 64
    // ---- inline fold step 1: stats -> sc/t ----
    if (tid < 128) {
        float s1 = 0.f, s2v = 0.f;
        for (int s = 0; s < nsl; ++s) { s1 += stats[s * 256 + tid]; s2v += stats[s * 256 + 128 + tid]; }
        float mean = s1 * inv_n;
        float var = s2v * inv_n - mean * mean;
        float sc = gamma[tid] * rsqrtf(var + 1e-5f);
        scL[tid] = sc;
        tL[tid] = beta[tid] - mean * sc;
    }
    __syncthreads();
    // ---- inline fold step 2: W[k][colbase+jl] -> Wl[jl*136+k] fp16 + bp ----
    {
        int jl = tid & 63, kg = tid >> 6;   // kg 0..3, k in [kg*32, kg*32+32)
        int j = colbase + jl;
        float pb = 0.f;
#pragma unroll
        for (int kk = 0; kk < 32; ++kk) {
            int k = kg * 32 + kk;
            float w = W[k * 128 + j];       // coalesced across j
            Wl[jl * 136 + k] = (_Float16)(scL[k] * w);
            pb += tL[k] * w;
        }
        pbp[kg][jl] = pb;
    }
    __syncthreads();
    if (tid < 64) bpL[tid] = pbp[0][tid] + pbp[1][tid] + pbp[2][tid] + pbp[3][tid];
    __syncthreads();

    int lane = tid & 63, wid = tid >> 6;            // wid 0..3
    int m = lane & 15, quad = lane >> 4;
    int rbase = row_blk * 64 + wid * 16;            // N_NODES % 16 == 0: no straddle
    bool act = rbase < n;
    const bool do_al = (asrc != nullptr);
    float st[4] = {}, s2t[4] = {};
    float ps[4][2] = {}, pd[4][2] = {};

    if (act) {
        const _Float16* arow = Ah + (size_t)(rbase + m) * 128 + quad * 8;
        h8 af0 = *(const h8*)(arow);
        h8 af1 = *(const h8*)(arow + 32);
        h8 af2 = *(const h8*)(arow + 64);
        h8 af3 = *(const h8*)(arow + 96);
#pragma unroll
        for (int t = 0; t < 4; ++t) {
            const _Float16* wrow = &Wl[(t * 16 + m) * 136 + quad * 8];
            f32x4 acc = {0.f, 0.f, 0.f, 0.f};
            acc = __builtin_amdgcn_mfma_f32_16x16x32_f16(af0, *(const h8*)(wrow), acc, 0, 0, 0);
            acc = __builtin_amdgcn_mfma_f32_16x16x32_f16(af1, *(const h8*)(wrow + 32), acc, 0, 0, 0);
            acc = __builtin_amdgcn_mfma_f32_16x16x32_f16(af2, *(const h8*)(wrow + 64), acc, 0, 0, 0);
            acc = __builtin_amdgcn_mfma_f32_16x16x32_f16(af3, *(const h8*)(wrow + 96), acc, 0, 0, 0);
            int jl = t * 16 + m;
            int j = colbase + jl;
            float bj = bpL[jl];
            float avs = 0.f, avd = 0.f;
            if (do_al) { avs = asrc[j]; avd = adst[j]; }
            int hh = t >> 1;    // local head 0..1
#pragma unroll
            for (int r = 0; r < 4; ++r) {
                float o = acc[r] + bj;
                if (do_al) {
                    ps[r][hh] += o * avs;
                    pd[r][hh] += o * avd;
                }
                float v = relu ? fmaxf(o, 0.f) : o;
                _Float16 hv16 = (_Float16)v;
                int row = rbase + quad * 4 + r;
                outh[(size_t)row * 128 + j] = hv16;
                if (do_st) {
                    float fv = (float)hv16;
                    st[t] += fv;
                    s2t[t] += fv * fv;
                }
            }
        }
        if (do_al) {
            int gh0 = colbase >> 5;   // global head base: 0 or 2
#pragma unroll
            for (int r = 0; r < 4; ++r) {
#pragma unroll
                for (int hh = 0; hh < 2; ++hh) {
                    float v = ps[r][hh];
                    v += __shfl_xor(v, 1, 64); v += __shfl_xor(v, 2, 64);
                    v += __shfl_xor(v, 4, 64); v += __shfl_xor(v, 8, 64);
                    float w = pd[r][hh];
                    w += __shfl_xor(w, 1, 64); w += __shfl_xor(w, 2, 64);
                    w += __shfl_xor(w, 4, 64); w += __shfl_xor(w, 8, 64);
                    if (m == 0) {
                        int row = rbase + quad * 4 + r;
                        als[row * 4 + gh0 + hh] = v;
                        ald[row * 4 + gh0 + hh] = w;
                    }
                }
            }
        }
    }
    if (do_st) {
#pragma unroll
        for (int t = 0; t < 4; ++t) {
            st[t] += __shfl_xor(st[t], 16, 64);  st[t] += __shfl_xor(st[t], 32, 64);
            s2t[t] += __shfl_xor(s2t[t], 16, 64); s2t[t] += __shfl_xor(s2t[t], 32, 64);
        }
        if (quad == 0 && act) {
#pragma unroll
            for (int t = 0; t < 4; ++t) {
                atomicAdd(&Sl2[t * 16 + m], st[t]);
                atomicAdd(&Sl2[64 + t * 16 + m], s2t[t]);
            }
        }
        __syncthreads();
        if (tid < 128) {
            int which = tid >> 6, c = tid & 63;
            atomicAdd(&stats8[(blockIdx.x & 7) * 256 + which * 128 + colbase + c],
                      Sl2[which * 64 + c]);
        }
    }
}

__device__ __forceinline__ float leaky(float x) { return fmaxf(x, 0.2f * x); }

// ---------------- GAT aggregation: wave=node, predicated 4-chain gather ----------------
// Padded CSR: row = col[node*DMAX .. node*DMAX+cnt), col is ushort (N<65536).
// 4 edge-quads x 16 feature-lanes; out-of-range chains clamp to last valid slot
// with weight 0. NO global atomics here (12500 blocks — round-1 lesson).
__global__ __launch_bounds__(256) void gat_aggregate(const _Float16* __restrict__ hp,
                                                     const float* __restrict__ al_s,
                                                     const float* __restrict__ al_d,
                                                     const int* __restrict__ cnt_arr,
                                                     const unsigned short* __restrict__ col,
                                                     const float* __restrict__ bias,
                                                     _Float16* __restrict__ h_out, int n) {
    int tid = threadIdx.x;
    int lane = tid & 63, wid = tid >> 6;
    int node = blockIdx.x * 4 + wid;  // N_NODES % 4 == 0
    int beg = node * DMAX;
    int end = beg + min(cnt_arr[node], DMAX);
    int q = lane >> 4, l4 = lane & 15;
    int head = l4 >> 2;
    int f0 = l4 * 8;
    float adh = al_d[node * 4 + head];
    float ch = leaky(adh);
    const _Float16* hpf = hp + f0;
    int last = end - 1;  // cnt >= 1 always (self-loop)
    float ws = 0.f;
    float a0 = 0.f, a1 = 0.f, a2 = 0.f, a3 = 0.f, a4 = 0.f, a5 = 0.f, a6 = 0.f, a7 = 0.f;
    for (int e = beg + q; e < end; e += 16) {
        int e1 = e + 4, e2 = e + 8, e3 = e + 12;
        bool v1 = e1 < end, v2 = e2 < end, v3 = e3 < end;
        unsigned s0 = (unsigned)col[e];
        unsigned s1 = (unsigned)col[v1 ? e1 : last];
        unsigned s2 = (unsigned)col[v2 ? e2 : last];
        unsigned s3 = (unsigned)col[v3 ? e3 : last];
        float as0 = al_s[s0 * 4 + head];
        float as1 = al_s[s1 * 4 + head];
        float as2 = al_s[s2 * 4 + head];
        float as3 = al_s[s3 * 4 + head];
        h8 hv0 = *(const h8*)(hpf + (size_t)s0 * 128);
        h8 hv1 = *(const h8*)(hpf + (size_t)s1 * 128);
        h8 hv2 = *(const h8*)(hpf + (size_t)s2 * 128);
        h8 hv3 = *(const h8*)(hpf + (size_t)s3 * 128);
        float w0 = __expf(fminf(leaky(as0 + adh) - ch, 10.f));
        float w1 = v1 ? __expf(fminf(leaky(as1 + adh) - ch, 10.f)) : 0.f;
        float w2 = v2 ? __expf(fminf(leaky(as2 + adh) - ch, 10.f)) : 0.f;
        float w3 = v3 ? __expf(fminf(leaky(as3 + adh) - ch, 10.f)) : 0.f;
        ws += (w0 + w1) + (w2 + w3);
        a0 += (float)hv0[0] * w0 + (float)hv1[0] * w1 + (float)hv2[0] * w2 + (float)hv3[0] * w3;
        a1 += (float)hv0[1] * w0 + (float)hv1[1] * w1 + (float)hv2[1] * w2 + (float)hv3[1] * w3;
        a2 += (float)hv0[2] * w0 + (float)hv1[2] * w1 + (float)hv2[2] * w2 + (float)hv3[2] * w3;
        a3 += (float)hv0[3] * w0 + (float)hv1[3] * w1 + (float)hv2[3] * w2 + (float)hv3[3] * w3;
        a4 += (float)hv0[4] * w0 + (float)hv1[4] * w1 + (float)hv2[4] * w2 + (float)hv3[4] * w3;
        a5 += (float)hv0[5] * w0 + (float)hv1[5] * w1 + (float)hv2[5] * w2 + (float)hv3[5] * w3;
        a6 += (float)hv0[6] * w0 + (float)hv1[6] * w1 + (float)hv2[6] * w2 + (float)hv3[6] * w3;
        a7 += (float)hv0[7] * w0 + (float)hv1[7] * w1 + (float)hv2[7] * w2 + (float)hv3[7] * w3;
    }
#pragma unroll
    for (int off = 16; off <= 32; off <<= 1) {
        ws += __shfl_xor(ws, off, 64);
        a0 += __shfl_xor(a0, off, 64); a1 += __shfl_xor(a1, off, 64);
        a2 += __shfl_xor(a2, off, 64); a3 += __shfl_xor(a3, off, 64);
        a4 += __shfl_xor(a4, off, 64); a5 += __shfl_xor(a5, off, 64);
        a6 += __shfl_xor(a6, off, 64); a7 += __shfl_xor(a7, off, 64);
    }
    if (q == 0) {
        float inv = 1.f / (ws + 1e-16f);
        float4 b0 = *(const float4*)&bias[f0];
        float4 b1 = *(const float4*)&bias[f0 + 4];
        h8 ov;
        ov[0] = (_Float16)fmaxf(a0 * inv + b0.x, 0.f);
        ov[1] = (_Float16)fmaxf(a1 * inv + b0.y, 0.f);
        ov[2] = (_Float16)fmaxf(a2 * inv + b0.z, 0.f);
        ov[3] = (_Float16)fmaxf(a3 * inv + b0.w, 0.f);
        ov[4] = (_Float16)fmaxf(a4 * inv + b1.x, 0.f);
        ov[5] = (_Float16)fmaxf(a5 * inv + b1.y, 0.f);
        ov[6] = (_Float16)fmaxf(a6 * inv + b1.z, 0.f);
        ov[7] = (_Float16)fmaxf(a7 * inv + b1.w, 0.f);
        *(h8*)&h_out[(size_t)node * 128 + f0] = ov;
    }
}

// ---------------- pooling (batch sorted), chunk=32 ----------------
__global__ void pool_kernel(const _Float16* __restrict__ h, const int* __restrict__ batch,
                            float* __restrict__ g, int n, int chunk) {
    int f = threadIdx.x;  // 128
    int a = blockIdx.x * chunk;
    if (a >= n) return;
    int b = min(n, a + chunk);
    float acc = 0.f;
    int cur = batch[a];
    for (int i = a; i < b; ++i) {
        int bi = batch[i];
        if (bi != cur) {
            atomicAdd(&g[cur * 128 + f], acc);
            acc = 0.f;
            cur = bi;
        }
        acc += (float)h[(size_t)i * 128 + f];
    }
    atomicAdd(&g[cur * 128 + f], acc);
}

// ---------------- head GEMM: block-local BN stats of A (prologue), BN inline,
// column stats of own output rows (epilogue, -> outstats for final_kernel) ----
__global__ __launch_bounds__(256) void gemm128_bn(const float* __restrict__ A,
                                                  const float* __restrict__ W,
                                                  const float* __restrict__ bias,
                                                  float inv_n,
                                                  const float* __restrict__ gamma,
                                                  const float* __restrict__ beta,
                                                  float* __restrict__ out,
                                                  float* __restrict__ outstats, int n) {
    __shared__ float Wl[128 * 128];
    __shared__ float hT[128 * 32];
    __shared__ float S[16][128], S2[16][128];
    __shared__ float sS[128], tS[128];
    int tid = threadIdx.x;
    for (int i = tid; i < 4096; i += 256) {
        ((float4*)Wl)[i] = ((const float4*)W)[i];
    }
    {
        int c8 = (tid & 15) * 8;
        int rg = tid >> 4;
        float s[8] = {}, s2[8] = {};
        for (int r = rg; r < n; r += 16) {
            const float4* p = (const float4*)&A[(size_t)r * 128 + c8];
            float4 v0 = p[0], v1 = p[1];
            float f[8] = {v0.x, v0.y, v0.z, v0.w, v1.x, v1.y, v1.z, v1.w};
#pragma unroll
            for (int i = 0; i < 8; ++i) { s[i] += f[i]; s2[i] += f[i] * f[i]; }
        }
#pragma unroll
        for (int i = 0; i < 8; ++i) { S[rg][c8 + i] = s[i]; S2[rg][c8 + i] = s2[i]; }
    }
    __syncthreads();
    if (tid < 128) {
        float a = 0.f, b2 = 0.f;
#pragma unroll
        for (int k = 0; k < 16; ++k) { a += S[k][tid]; b2 += S2[k][tid]; }
        float m = a * inv_n;
        float var = b2 * inv_n - m * m;
        float sc = gamma[tid] * rsqrtf(var + 1e-5f);
        sS[tid] = sc;
        tS[tid] = beta[tid] - m * sc;
    }
    __syncthreads();
    int base = blockIdx.x * 32;
    for (int pass = 0; pass < 4; ++pass) {
        int r = (tid >> 5) + pass * 8;
        int c4 = tid & 31;
        int row = base + r;
        float4 v = (row < n) ? ((const float4*)(A + (size_t)row * 128))[c4]
                             : make_float4(0.f, 0.f, 0.f, 0.f);
        int c0 = c4 * 4;
        hT[(c0 + 0) * 32 + r] = v.x * sS[c0 + 0] + tS[c0 + 0];
        hT[(c0 + 1) * 32 + r] = v.y * sS[c0 + 1] + tS[c0 + 1];
        hT[(c0 + 2) * 32 + r] = v.z * sS[c0 + 2] + tS[c0 + 2];
        hT[(c0 + 3) * 32 + r] = v.w * sS[c0 + 3] + tS[c0 + 3];
    }
    __syncthreads();
    int tx = tid & 31, ty = tid >> 5;
    int j0 = tx * 4, r0 = ty * 4;
    float acc[4][4] = {};
#pragma unroll 8
    for (int k = 0; k < 128; ++k) {
        float4 a = *(const float4*)&hT[k * 32 + r0];
        float4 w = *(const float4*)&Wl[k * 128 + j0];
        acc[0][0] += a.x * w.x; acc[0][1] += a.x * w.y; acc[0][2] += a.x * w.z; acc[0][3] += a.x * w.w;
        acc[1][0] += a.y * w.x; acc[1][1] += a.y * w.y; acc[1][2] += a.y * w.z; acc[1][3] += a.y * w.w;
        acc[2][0] += a.z * w.x; acc[2][1] += a.z * w.y; acc[2][2] += a.z * w.z; acc[2][3] += a.z * w.w;
        acc[3][0] += a.w * w.x; acc[3][1] += a.w * w.y; acc[3][2] += a.w * w.z; acc[3][3] += a.w * w.w;
    }
    float4 bb = *(const float4*)&bias[j0];
    float csum[4] = {}, csq[4] = {};
    for (int i2 = 0; i2 < 4; ++i2) {
        int row = base + r0 + i2;
        if (row < n) {
            float o0 = fmaxf(acc[i2][0] + bb.x, 0.f);
            float o1 = fmaxf(acc[i2][1] + bb.y, 0.f);
            float o2 = fmaxf(acc[i2][2] + bb.z, 0.f);
            float o3 = fmaxf(acc[i2][3] + bb.w, 0.f);
            *(float4*)&out[(size_t)row * 128 + j0] = make_float4(o0, o1, o2, o3);
            csum[0] += o0; csum[1] += o1; csum[2] += o2; csum[3] += o3;
            csq[0] += o0 * o0; csq[1] += o1 * o1; csq[2] += o2 * o2; csq[3] += o3 * o3;
        }
    }
#pragma unroll
    for (int c = 0; c < 4; ++c) {
        atomicAdd(&outstats[j0 + c], csum[c]);
        atomicAdd(&outstats[128 + j0 + c], csq[c]);
    }
}

// ---------------- final: inline BN + classifier + log_softmax ----------------
__global__ __launch_bounds__(64) void final_kernel(const float* __restrict__ g2,
                                                   const float* __restrict__ stats, float inv_n,
                                                   const float* __restrict__ gamma,
                                                   const float* __restrict__ beta,
                                                   const float* __restrict__ W,
                                                   const float* __restrict__ b,
                                                   float* __restrict__ out, int rows) {
    int r = blockIdx.x;
    if (r >= rows) return;
    int lane = threadIdx.x;
    float logit[10] = {};
    for (int k = lane; k < 128; k += 64) {
        float m = stats[k] * inv_n;
        float var = stats[128 + k] * inv_n - m * m;
        float sc = gamma[k] * rsqrtf(var + 1e-5f);
        float gv = (g2[r * 128 + k] - m) * sc + beta[k];
#pragma unroll
        for (int j = 0; j < 10; ++j) logit[j] += gv * W[k * 10 + j];
    }
#pragma unroll
    for (int j = 0; j < 10; ++j)
        for (int off = 1; off < 64; off <<= 1) logit[j] += __shfl_xor(logit[j], off, 64);
    if (lane == 0) {
        float m = -1e30f;
#pragma unroll
        for (int j = 0; j < 10; ++j) { logit[j] += b[j]; m = fmaxf(m, logit[j]); }
        float sum = 0.f;
#pragma unroll
        for (int j = 0; j < 10; ++j) sum += expf(logit[j] - m);
        float lse = m + logf(sum);
#pragma unroll
        for (int j = 0; j < 10; ++j) out[r * 10 + j] = logit[j] - lse;
    }
}

extern "C" void kernel_launch(void* const* d_in, const int* in_sizes, int n_in,
                              void* d_out, int out_size, void* d_ws, size_t ws_size,
                              hipStream_t stream) {
    const float* x      = (const float*)d_in[0];
    const int*   ei     = (const int*)d_in[1];
    const int*   batch  = (const int*)d_in[2];
    const float* w_feat = (const float*)d_in[3];
    const float* bnf_g  = (const float*)d_in[4];
    const float* bnf_b  = (const float*)d_in[5];
    const float* bnc_g  = (const float*)d_in[6];
    const float* bnc_b  = (const float*)d_in[7];
    const float* gat_w  = (const float*)d_in[8];
    const float* gat_as = (const float*)d_in[9];
    const float* gat_ad = (const float*)d_in[10];
    const float* gat_b  = (const float*)d_in[11];
    const float* bnfc_g = (const float*)d_in[12];
    const float* bnfc_b = (const float*)d_in[13];
    const float* lin_w  = (const float*)d_in[14];
    const float* lin_b  = (const float*)d_in[15];
    const float* bnh_g  = (const float*)d_in[16];
    const float* bnh_b  = (const float*)d_in[17];
    const float* cls_w  = (const float*)d_in[18];
    const float* cls_b  = (const float*)d_in[19];
    float* out = (float*)d_out;

    char* ws = (char*)d_ws;
    size_t off = 0;
    auto alloc = [&](size_t bytes) -> void* {
        void* p = ws + off;
        off = (off + bytes + 255) & ~(size_t)255;
        return p;
    };
    _Float16* xh   = (_Float16*)alloc((size_t)N_NODES * 128 * 2);
    _Float16* h    = (_Float16*)alloc((size_t)N_NODES * 128 * 2);
    _Float16* hp   = (_Float16*)alloc((size_t)N_NODES * 128 * 2);
    float*    als  = (float*)alloc((size_t)N_NODES * 4 * 4);
    float*    ald  = (float*)alloc((size_t)N_NODES * 4 * 4);
    int*      curs = (int*)alloc((size_t)N_NODES * 4);
    unsigned short* col = (unsigned short*)alloc((size_t)N_NODES * DMAX * 2);
    float*    SB   = (float*)alloc(SB_TOT * 4);
    float*    g    = (float*)alloc(NGRAPHS * 128 * 4);
    float*    g2   = (float*)alloc(NGRAPHS * 128 * 4);

    const int* esrc = ei;
    const int* edst = ei + N_EDGES;
    const float fin = 1.f / N_NODES;

    // ---- init (zero SB incl BOTH conv stat buffers; self-loop slot 0; cursor=1) ----
    init_kernel<<<divup(N_NODES, 256), 256, 0, stream>>>(SB, curs, col, N_NODES);

    // ---- cast + feat stats ----
    cast_stats<<<256, 256, 0, stream>>>(x, xh, N_NODES, SB + SB_X);

    // ---- feat gemm: inline fold from SB_X (nsl=1); stats of h -> CONV0;
    //      carries scatter chunks 0..HALF0-1 ----
    gemm_mfma<<<GEMM_BLOCKS + HALF0 * 8, 256, 0, stream>>>(
        xh, w_feat, bnf_g, bnf_b, SB + SB_X, 1, fin,
        h, N_NODES, 1,
        nullptr, nullptr, nullptr, nullptr,
        SB + SB_CONV0, nullptr, nullptr,
        esrc, edst, curs, col, N_EDGES, 0);

    // ---- 3 GAT conv layers; stats double-buffer CONV0/CONV1:
    // conv0 fold<-CONV0 (CONV1 init-zeroed), colstats0 -> CONV1
    // conv1 fold<-CONV1, zeroes CONV0,       colstats1 -> CONV0
    // conv2 fold<-CONV0, zeroes g (pool target)
    for (int i = 0; i < NCONV; ++i) {
        const float* foldsrc = (i == 1) ? SB + SB_CONV1 : SB + SB_CONV0;
        float* sz = (i == 1) ? SB + SB_CONV0 : nullptr;
        float* gz = (i == 2) ? g : nullptr;
        int nblk = GEMM_BLOCKS + ((i == 0) ? (NCHUNKS - HALF0) * 8 : 0);
        gemm_mfma<<<nblk, 256, 0, stream>>>(
            h, gat_w + 16384 * i, bnc_g + 128 * i, bnc_b + 128 * i, foldsrc, 8, fin,
            hp, N_NODES, 0,
            gat_as + 128 * i, gat_ad + 128 * i,
            als, ald, nullptr, sz, gz,
            (i == 0) ? esrc : nullptr, (i == 0) ? edst : nullptr,
            (i == 0) ? curs : nullptr, (i == 0) ? col : nullptr,
            (i == 0) ? N_EDGES : 0, HALF0);
        gat_aggregate<<<N_NODES / 4, 256, 0, stream>>>(hp, als, ald, curs, col,
                                                       gat_b + 128 * i, h, N_NODES);
        if (i < NCONV - 1)
            colstats_h<<<256, 256, 0, stream>>>(h, N_NODES,
                                                (i == 0) ? SB + SB_CONV1 : SB + SB_CONV0);
    }

    // ---- pool + MLP head (BN stats in-kernel; epilogue fills SB_H2 for final) ----
    pool_kernel<<<divup(N_NODES, 32), 128, 0, stream>>>(h, batch, g, N_NODES, 32);
    gemm128_bn<<<divup(NGRAPHS, 32), 256, 0, stream>>>(g, lin_w, lin_b, 1.f / NGRAPHS,
                                                       bnfc_g, bnfc_b, g2, SB + SB_H2, NGRAPHS);
    final_kernel<<<NGRAPHS, 64, 0, stream>>>(g2, SB + SB_H2, 1.f / NGRAPHS, bnh_g, bnh_b,
                                             cls_w, cls_b, out, NGRAPHS);
}

// Round 10
// 362.507 us; speedup vs baseline: 1.0181x; 1.0181x over previous
//
#include <hip/hip_runtime.h>
#include <math.h>

#define N_NODES 50000
#define N_EDGES 800000
#define NGRAPHS 256
#define NCONV 3
#define DMAX 64   // padded CSR row stride; max in-degree+1 (Binomial mean 16) << 64
#define GEMM_BLOCKS 391  // divup(N_NODES, 128)
#define SCHUNK 4096      // edges per scatter block (512 thr x 8 iters)
#define NCHUNKS 196      // divup(N_EDGES, SCHUNK)
#define HALF0 98         // chunks 0..97 ride feat-gemm; 98..195 ride conv0-gemm

typedef _Float16 h4 __attribute__((ext_vector_type(4)));
typedef _Float16 h8 __attribute__((ext_vector_type(8)));
typedef float f32x4 __attribute__((ext_vector_type(4)));

static inline int divup(int a, int b) { return (a + b - 1) / b; }

// SB layout (floats): double-buffered 8-sliced conv stats (CONV0/CONV1 — the
// in-gemm fold READS one buffer while blocks 0..3 ZERO the other; never same),
// feat stats X, head stats H2. Stats atomics only from <=782-block kernels
// (round-1 lesson: 12500-block atomics into 8KB = 200+ us wall).
#define SB_CONV0 0
#define SB_CONV1 2048
#define SB_X 4096
#define SB_H2 4352
#define SB_TOT 4608

// ---------------- init: zero SB (BEFORE any stats accumulation), self-loops ----------------
__global__ void init_kernel(float* __restrict__ SB, int* __restrict__ cursor,
                            unsigned short* __restrict__ col, int n) {
    int i = blockIdx.x * blockDim.x + threadIdx.x;
    if (i < SB_TOT) SB[i] = 0.f;
    if (i < n) {
        cursor[i] = 1;              // slot 0 = self-loop
        col[(size_t)i * DMAX] = (unsigned short)i;
    }
}

// ---------------- cast f32->f16 + column stats ----------
__global__ __launch_bounds__(256) void cast_stats(const float* __restrict__ x,
                                                  _Float16* __restrict__ y, int n,
                                                  float* __restrict__ sums) {
    __shared__ float S[16][128], S2[16][128];
    int tid = threadIdx.x;
    int c8 = (tid & 15) * 8;
    int rg = tid >> 4;
    float s[8] = {}, s2[8] = {};
    for (int r = blockIdx.x * 16 + rg; r < n; r += gridDim.x * 16) {
        const float4* p = (const float4*)&x[(size_t)r * 128 + c8];
        float4 v0 = p[0], v1 = p[1];
        float f[8] = {v0.x, v0.y, v0.z, v0.w, v1.x, v1.y, v1.z, v1.w};
        h8 o;
#pragma unroll
        for (int i = 0; i < 8; ++i) {
            o[i] = (_Float16)f[i];
            s[i] += f[i];
            s2[i] += f[i] * f[i];
        }
        *(h8*)&y[(size_t)r * 128 + c8] = o;
    }
#pragma unroll
    for (int i = 0; i < 8; ++i) { S[rg][c8 + i] = s[i]; S2[rg][c8 + i] = s2[i]; }
    __syncthreads();
    if (tid < 128) {
        float a = 0.f, b = 0.f;
#pragma unroll
        for (int k = 0; k < 16; ++k) { a += S[k][tid]; b += S2[k][tid]; }
        atomicAdd(&sums[tid], a);
        atomicAdd(&sums[128 + tid], b);
    }
}

// ---------------- column stats, fp16 input (256 blocks -> slice 0..7 by blockIdx&7) ----------
__global__ __launch_bounds__(256) void colstats_h(const _Float16* __restrict__ x, int n,
                                                  float* __restrict__ sums) {
    __shared__ float S[16][128], S2[16][128];
    int tid = threadIdx.x;
    int c8 = (tid & 15) * 8;
    int rg = tid >> 4;
    float s[8] = {}, s2[8] = {};
    for (int r = blockIdx.x * 16 + rg; r < n; r += gridDim.x * 16) {
        h8 v = *(const h8*)&x[(size_t)r * 128 + c8];
#pragma unroll
        for (int i = 0; i < 8; ++i) {
            float f = (float)v[i];
            s[i] += f;
            s2[i] += f * f;
        }
    }
#pragma unroll
    for (int i = 0; i < 8; ++i) { S[rg][c8 + i] = s[i]; S2[rg][c8 + i] = s2[i]; }
    __syncthreads();
    if (tid < 128) {
        float a = 0.f, b = 0.f;
#pragma unroll
        for (int k = 0; k < 16; ++k) { a += S[k][tid]; b += S2[k][tid]; }
        atomicAdd(&sums[(blockIdx.x & 7) * 256 + tid], a);
        atomicAdd(&sums[(blockIdx.x & 7) * 256 + 128 + tid], b);
    }
}

// ---------------- MFMA fp16 GEMM with INLINE BN-fold ----------------
// Each block redundantly computes the fold (stats -> sc/t -> scaled/transposed
// fp16 W into LDS + folded bias bp) — W is 64KB L2-hot broadcast, ~1us/block,
// overlapped. Removes the 4 fold_t dispatches + WTh/bp round-trips.
// 512 threads / 8 waves / 128 rows per block; ~39.4KB LDS -> 4 blk/CU = 32 waves.
// Scatter tail blocks (blockIdx >= GEMM_BLOCKS) as in r7 (return pre-barrier).
// sums_zero: zero the OTHER stats buffer (double-buffered; fold reads its own).
// r9 lesson: do NOT N-split this kernel — doubling blocks doubles fold
// overhead + A traffic and regresses (369 vs 363).
__global__ __launch_bounds__(512) void gemm_mfma(const _Float16* __restrict__ Ah,
                                                 const float* __restrict__ W,
                                                 const float* __restrict__ gamma,
                                                 const float* __restrict__ beta,
                                                 const float* __restrict__ stats, int nsl,
                                                 float inv_n,
                                                 _Float16* __restrict__ outh, int n, int relu,
                                                 const float* __restrict__ asrc,
                                                 const float* __restrict__ adst,
                                                 float* __restrict__ als,
                                                 float* __restrict__ ald,
                                                 float* __restrict__ stats8,
                                                 float* __restrict__ sums_zero,
                                                 float* __restrict__ g_zero,
                                                 const int* __restrict__ s_src,
                                                 const int* __restrict__ s_dst,
                                                 int* __restrict__ s_cursor,
                                                 unsigned short* __restrict__ s_col,
                                                 int s_E, int s_chunk0) {
    __shared__ _Float16 Wl[128 * 136];
    __shared__ float Sl2[256];           // stats epilogue accumulator
    __shared__ float scL[128], tL[128];  // BN scale / shift
    __shared__ float pbp[4][128];        // bp partials
    __shared__ float bpL[128];           // folded bias
    int tid = threadIdx.x;
    if ((int)blockIdx.x >= GEMM_BLOCKS) {
        // ---- scatter tail: XCD-sliced padded-CSR edge scatter ----
        int sb = blockIdx.x - GEMM_BLOCKS;
        int slice = sb & 7;
        int chunk = s_chunk0 + (sb >> 3);
        int base = chunk * SCHUNK;
        int lim = min(base + SCHUNK, s_E);
        int lo = slice * (N_NODES / 8);
        int hi = lo + (N_NODES / 8);
        for (int i = base + tid; i < lim; i += 512) {
            int d = s_dst[i];
            if (d >= lo && d < hi) {
                int p = atomicAdd(&s_cursor[d], 1);
                if (p < DMAX) s_col[(size_t)d * DMAX + p] = (unsigned short)s_src[i];
            }
        }
        return;  // before any barrier
    }
    if (sums_zero && blockIdx.x < 4) sums_zero[blockIdx.x * 512 + tid] = 0.f;
    if (g_zero && blockIdx.x < 64) g_zero[blockIdx.x * 512 + tid] = 0.f;
    const bool do_st = (stats8 != nullptr);
    if (do_st && tid < 256) Sl2[tid] = 0.f;
    // ---- inline fold step 1: stats -> sc/t ----
    if (tid < 128) {
        float s1 = 0.f, s2v = 0.f;
        for (int s = 0; s < nsl; ++s) { s1 += stats[s * 256 + tid]; s2v += stats[s * 256 + 128 + tid]; }
        float mean = s1 * inv_n;
        float var = s2v * inv_n - mean * mean;
        float sc = gamma[tid] * rsqrtf(var + 1e-5f);
        scL[tid] = sc;
        tL[tid] = beta[tid] - mean * sc;
    }
    __syncthreads();
    // ---- inline fold step 2: W (f32, row-major [k][j]) -> Wl[j*136+k] fp16 + bp ----
    {
        int j = tid & 127, kg = tid >> 7;   // kg 0..3, k in [kg*32, kg*32+32)
        float pb = 0.f;
#pragma unroll
        for (int kk = 0; kk < 32; ++kk) {
            int k = kg * 32 + kk;
            float w = W[k * 128 + j];       // coalesced across j
            Wl[j * 136 + k] = (_Float16)(scL[k] * w);
            pb += tL[k] * w;
        }
        pbp[kg][j] = pb;
    }
    __syncthreads();
    if (tid < 128) bpL[tid] = pbp[0][tid] + pbp[1][tid] + pbp[2][tid] + pbp[3][tid];
    __syncthreads();

    int lane = tid & 63, wid = tid >> 6;            // wid 0..7
    int m = lane & 15, quad = lane >> 4;
    int rbase = blockIdx.x * 128 + wid * 16;        // N_NODES % 16 == 0: no straddle
    bool act = rbase < n;
    const bool do_al = (asrc != nullptr);
    float st[8] = {}, s2t[8] = {};
    float ps[4][4] = {}, pd[4][4] = {};

    if (act) {
        const _Float16* arow = Ah + (size_t)(rbase + m) * 128 + quad * 8;
        h8 af0 = *(const h8*)(arow);
        h8 af1 = *(const h8*)(arow + 32);
        h8 af2 = *(const h8*)(arow + 64);
        h8 af3 = *(const h8*)(arow + 96);
#pragma unroll
        for (int t = 0; t < 8; ++t) {
            const _Float16* wrow = &Wl[(t * 16 + m) * 136 + quad * 8];
            f32x4 acc = {0.f, 0.f, 0.f, 0.f};
            acc = __builtin_amdgcn_mfma_f32_16x16x32_f16(af0, *(const h8*)(wrow), acc, 0, 0, 0);
            acc = __builtin_amdgcn_mfma_f32_16x16x32_f16(af1, *(const h8*)(wrow + 32), acc, 0, 0, 0);
            acc = __builtin_amdgcn_mfma_f32_16x16x32_f16(af2, *(const h8*)(wrow + 64), acc, 0, 0, 0);
            acc = __builtin_amdgcn_mfma_f32_16x16x32_f16(af3, *(const h8*)(wrow + 96), acc, 0, 0, 0);
            int j = t * 16 + m;
            float bj = bpL[j];
            float avs = 0.f, avd = 0.f;
            if (do_al) { avs = asrc[j]; avd = adst[j]; }
            int hh = t >> 1;
#pragma unroll
            for (int r = 0; r < 4; ++r) {
                float o = acc[r] + bj;
                if (do_al) {
                    ps[r][hh] += o * avs;
                    pd[r][hh] += o * avd;
                }
                float v = relu ? fmaxf(o, 0.f) : o;
                _Float16 hv16 = (_Float16)v;
                int row = rbase + quad * 4 + r;
                outh[(size_t)row * 128 + j] = hv16;
                if (do_st) {
                    float fv = (float)hv16;
                    st[t] += fv;
                    s2t[t] += fv * fv;
                }
            }
        }
        if (do_al) {
#pragma unroll
            for (int r = 0; r < 4; ++r) {
#pragma unroll
                for (int hh = 0; hh < 4; ++hh) {
                    float v = ps[r][hh];
                    v += __shfl_xor(v, 1, 64); v += __shfl_xor(v, 2, 64);
                    v += __shfl_xor(v, 4, 64); v += __shfl_xor(v, 8, 64);
                    float w = pd[r][hh];
                    w += __shfl_xor(w, 1, 64); w += __shfl_xor(w, 2, 64);
                    w += __shfl_xor(w, 4, 64); w += __shfl_xor(w, 8, 64);
                    if (m == 0) {
                        int row = rbase + quad * 4 + r;
                        als[row * 4 + hh] = v;
                        ald[row * 4 + hh] = w;
                    }
                }
            }
        }
    }
    if (do_st) {
#pragma unroll
        for (int t = 0; t < 8; ++t) {
            st[t] += __shfl_xor(st[t], 16, 64);  st[t] += __shfl_xor(st[t], 32, 64);
            s2t[t] += __shfl_xor(s2t[t], 16, 64); s2t[t] += __shfl_xor(s2t[t], 32, 64);
        }
        if (quad == 0 && act) {
#pragma unroll
            for (int t = 0; t < 8; ++t) {
                atomicAdd(&Sl2[t * 16 + m], st[t]);
                atomicAdd(&Sl2[128 + t * 16 + m], s2t[t]);
            }
        }
        __syncthreads();
        if (tid < 256) atomicAdd(&stats8[(blockIdx.x & 7) * 256 + tid], Sl2[tid]);
    }
}

__device__ __forceinline__ float leaky(float x) { return fmaxf(x, 0.2f * x); }

// ---------------- GAT aggregation: wave=node, predicated 4-chain gather ----------------
// Padded CSR: row = col[node*DMAX .. node*DMAX+cnt), col is ushort (N<65536).
// 4 edge-quads x 16 feature-lanes; out-of-range chains clamp to last valid slot
// with weight 0. NO global atomics here (12500 blocks — round-1 lesson).
__global__ __launch_bounds__(256) void gat_aggregate(const _Float16* __restrict__ hp,
                                                     const float* __restrict__ al_s,
                                                     const float* __restrict__ al_d,
                                                     const int* __restrict__ cnt_arr,
                                                     const unsigned short* __restrict__ col,
                                                     const float* __restrict__ bias,
                                                     _Float16* __restrict__ h_out, int n) {
    int tid = threadIdx.x;
    int lane = tid & 63, wid = tid >> 6;
    int node = blockIdx.x * 4 + wid;  // N_NODES % 4 == 0
    int beg = node * DMAX;
    int end = beg + min(cnt_arr[node], DMAX);
    int q = lane >> 4, l4 = lane & 15;
    int head = l4 >> 2;
    int f0 = l4 * 8;
    float adh = al_d[node * 4 + head];
    float ch = leaky(adh);
    const _Float16* hpf = hp + f0;
    int last = end - 1;  // cnt >= 1 always (self-loop)
    float ws = 0.f;
    float a0 = 0.f, a1 = 0.f, a2 = 0.f, a3 = 0.f, a4 = 0.f, a5 = 0.f, a6 = 0.f, a7 = 0.f;
    for (int e = beg + q; e < end; e += 16) {
        int e1 = e + 4, e2 = e + 8, e3 = e + 12;
        bool v1 = e1 < end, v2 = e2 < end, v3 = e3 < end;
        unsigned s0 = (unsigned)col[e];
        unsigned s1 = (unsigned)col[v1 ? e1 : last];
        unsigned s2 = (unsigned)col[v2 ? e2 : last];
        unsigned s3 = (unsigned)col[v3 ? e3 : last];
        float as0 = al_s[s0 * 4 + head];
        float as1 = al_s[s1 * 4 + head];
        float as2 = al_s[s2 * 4 + head];
        float as3 = al_s[s3 * 4 + head];
        h8 hv0 = *(const h8*)(hpf + (size_t)s0 * 128);
        h8 hv1 = *(const h8*)(hpf + (size_t)s1 * 128);
        h8 hv2 = *(const h8*)(hpf + (size_t)s2 * 128);
        h8 hv3 = *(const h8*)(hpf + (size_t)s3 * 128);
        float w0 = __expf(fminf(leaky(as0 + adh) - ch, 10.f));
        float w1 = v1 ? __expf(fminf(leaky(as1 + adh) - ch, 10.f)) : 0.f;
        float w2 = v2 ? __expf(fminf(leaky(as2 + adh) - ch, 10.f)) : 0.f;
        float w3 = v3 ? __expf(fminf(leaky(as3 + adh) - ch, 10.f)) : 0.f;
        ws += (w0 + w1) + (w2 + w3);
        a0 += (float)hv0[0] * w0 + (float)hv1[0] * w1 + (float)hv2[0] * w2 + (float)hv3[0] * w3;
        a1 += (float)hv0[1] * w0 + (float)hv1[1] * w1 + (float)hv2[1] * w2 + (float)hv3[1] * w3;
        a2 += (float)hv0[2] * w0 + (float)hv1[2] * w1 + (float)hv2[2] * w2 + (float)hv3[2] * w3;
        a3 += (float)hv0[3] * w0 + (float)hv1[3] * w1 + (float)hv2[3] * w2 + (float)hv3[3] * w3;
        a4 += (float)hv0[4] * w0 + (float)hv1[4] * w1 + (float)hv2[4] * w2 + (float)hv3[4] * w3;
        a5 += (float)hv0[5] * w0 + (float)hv1[5] * w1 + (float)hv2[5] * w2 + (float)hv3[5] * w3;
        a6 += (float)hv0[6] * w0 + (float)hv1[6] * w1 + (float)hv2[6] * w2 + (float)hv3[6] * w3;
        a7 += (float)hv0[7] * w0 + (float)hv1[7] * w1 + (float)hv2[7] * w2 + (float)hv3[7] * w3;
    }
#pragma unroll
    for (int off = 16; off <= 32; off <<= 1) {
        ws += __shfl_xor(ws, off, 64);
        a0 += __shfl_xor(a0, off, 64); a1 += __shfl_xor(a1, off, 64);
        a2 += __shfl_xor(a2, off, 64); a3 += __shfl_xor(a3, off, 64);
        a4 += __shfl_xor(a4, off, 64); a5 += __shfl_xor(a5, off, 64);
        a6 += __shfl_xor(a6, off, 64); a7 += __shfl_xor(a7, off, 64);
    }
    if (q == 0) {
        float inv = 1.f / (ws + 1e-16f);
        float4 b0 = *(const float4*)&bias[f0];
        float4 b1 = *(const float4*)&bias[f0 + 4];
        h8 ov;
        ov[0] = (_Float16)fmaxf(a0 * inv + b0.x, 0.f);
        ov[1] = (_Float16)fmaxf(a1 * inv + b0.y, 0.f);
        ov[2] = (_Float16)fmaxf(a2 * inv + b0.z, 0.f);
        ov[3] = (_Float16)fmaxf(a3 * inv + b0.w, 0.f);
        ov[4] = (_Float16)fmaxf(a4 * inv + b1.x, 0.f);
        ov[5] = (_Float16)fmaxf(a5 * inv + b1.y, 0.f);
        ov[6] = (_Float16)fmaxf(a6 * inv + b1.z, 0.f);
        ov[7] = (_Float16)fmaxf(a7 * inv + b1.w, 0.f);
        *(h8*)&h_out[(size_t)node * 128 + f0] = ov;
    }
}

// ---------------- pooling (batch sorted), chunk=32 ----------------
__global__ void pool_kernel(const _Float16* __restrict__ h, const int* __restrict__ batch,
                            float* __restrict__ g, int n, int chunk) {
    int f = threadIdx.x;  // 128
    int a = blockIdx.x * chunk;
    if (a >= n) return;
    int b = min(n, a + chunk);
    float acc = 0.f;
    int cur = batch[a];
    for (int i = a; i < b; ++i) {
        int bi = batch[i];
        if (bi != cur) {
            atomicAdd(&g[cur * 128 + f], acc);
            acc = 0.f;
            cur = bi;
        }
        acc += (float)h[(size_t)i * 128 + f];
    }
    atomicAdd(&g[cur * 128 + f], acc);
}

// ---------------- head GEMM: block-local BN stats of A (prologue), BN inline,
// column stats of own output rows (epilogue, -> outstats for final_kernel) ----
__global__ __launch_bounds__(256) void gemm128_bn(const float* __restrict__ A,
                                                  const float* __restrict__ W,
                                                  const float* __restrict__ bias,
                                                  float inv_n,
                                                  const float* __restrict__ gamma,
                                                  const float* __restrict__ beta,
                                                  float* __restrict__ out,
                                                  float* __restrict__ outstats, int n) {
    __shared__ float Wl[128 * 128];
    __shared__ float hT[128 * 32];
    __shared__ float S[16][128], S2[16][128];
    __shared__ float sS[128], tS[128];
    int tid = threadIdx.x;
    for (int i = tid; i < 4096; i += 256) {
        ((float4*)Wl)[i] = ((const float4*)W)[i];
    }
    {
        int c8 = (tid & 15) * 8;
        int rg = tid >> 4;
        float s[8] = {}, s2[8] = {};
        for (int r = rg; r < n; r += 16) {
            const float4* p = (const float4*)&A[(size_t)r * 128 + c8];
            float4 v0 = p[0], v1 = p[1];
            float f[8] = {v0.x, v0.y, v0.z, v0.w, v1.x, v1.y, v1.z, v1.w};
#pragma unroll
            for (int i = 0; i < 8; ++i) { s[i] += f[i]; s2[i] += f[i] * f[i]; }
        }
#pragma unroll
        for (int i = 0; i < 8; ++i) { S[rg][c8 + i] = s[i]; S2[rg][c8 + i] = s2[i]; }
    }
    __syncthreads();
    if (tid < 128) {
        float a = 0.f, b2 = 0.f;
#pragma unroll
        for (int k = 0; k < 16; ++k) { a += S[k][tid]; b2 += S2[k][tid]; }
        float m = a * inv_n;
        float var = b2 * inv_n - m * m;
        float sc = gamma[tid] * rsqrtf(var + 1e-5f);
        sS[tid] = sc;
        tS[tid] = beta[tid] - m * sc;
    }
    __syncthreads();
    int base = blockIdx.x * 32;
    for (int pass = 0; pass < 4; ++pass) {
        int r = (tid >> 5) + pass * 8;
        int c4 = tid & 31;
        int row = base + r;
        float4 v = (row < n) ? ((const float4*)(A + (size_t)row * 128))[c4]
                             : make_float4(0.f, 0.f, 0.f, 0.f);
        int c0 = c4 * 4;
        hT[(c0 + 0) * 32 + r] = v.x * sS[c0 + 0] + tS[c0 + 0];
        hT[(c0 + 1) * 32 + r] = v.y * sS[c0 + 1] + tS[c0 + 1];
        hT[(c0 + 2) * 32 + r] = v.z * sS[c0 + 2] + tS[c0 + 2];
        hT[(c0 + 3) * 32 + r] = v.w * sS[c0 + 3] + tS[c0 + 3];
    }
    __syncthreads();
    int tx = tid & 31, ty = tid >> 5;
    int j0 = tx * 4, r0 = ty * 4;
    float acc[4][4] = {};
#pragma unroll 8
    for (int k = 0; k < 128; ++k) {
        float4 a = *(const float4*)&hT[k * 32 + r0];
        float4 w = *(const float4*)&Wl[k * 128 + j0];
        acc[0][0] += a.x * w.x; acc[0][1] += a.x * w.y; acc[0][2] += a.x * w.z; acc[0][3] += a.x * w.w;
        acc[1][0] += a.y * w.x; acc[1][1] += a.y * w.y; acc[1][2] += a.y * w.z; acc[1][3] += a.y * w.w;
        acc[2][0] += a.z * w.x; acc[2][1] += a.z * w.y; acc[2][2] += a.z * w.z; acc[2][3] += a.z * w.w;
        acc[3][0] += a.w * w.x; acc[3][1] += a.w * w.y; acc[3][2] += a.w * w.z; acc[3][3] += a.w * w.w;
    }
    float4 bb = *(const float4*)&bias[j0];
    float csum[4] = {}, csq[4] = {};
    for (int i2 = 0; i2 < 4; ++i2) {
        int row = base + r0 + i2;
        if (row < n) {
            float o0 = fmaxf(acc[i2][0] + bb.x, 0.f);
            float o1 = fmaxf(acc[i2][1] + bb.y, 0.f);
            float o2 = fmaxf(acc[i2][2] + bb.z, 0.f);
            float o3 = fmaxf(acc[i2][3] + bb.w, 0.f);
            *(float4*)&out[(size_t)row * 128 + j0] = make_float4(o0, o1, o2, o3);
            csum[0] += o0; csum[1] += o1; csum[2] += o2; csum[3] += o3;
            csq[0] += o0 * o0; csq[1] += o1 * o1; csq[2] += o2 * o2; csq[3] += o3 * o3;
        }
    }
#pragma unroll
    for (int c = 0; c < 4; ++c) {
        atomicAdd(&outstats[j0 + c], csum[c]);
        atomicAdd(&outstats[128 + j0 + c], csq[c]);
    }
}

// ---------------- final: inline BN + classifier + log_softmax ----------------
__global__ __launch_bounds__(64) void final_kernel(const float* __restrict__ g2,
                                                   const float* __restrict__ stats, float inv_n,
                                                   const float* __restrict__ gamma,
                                                   const float* __restrict__ beta,
                                                   const float* __restrict__ W,
                                                   const float* __restrict__ b,
                                                   float* __restrict__ out, int rows) {
    int r = blockIdx.x;
    if (r >= rows) return;
    int lane = threadIdx.x;
    float logit[10] = {};
    for (int k = lane; k < 128; k += 64) {
        float m = stats[k] * inv_n;
        float var = stats[128 + k] * inv_n - m * m;
        float sc = gamma[k] * rsqrtf(var + 1e-5f);
        float gv = (g2[r * 128 + k] - m) * sc + beta[k];
#pragma unroll
        for (int j = 0; j < 10; ++j) logit[j] += gv * W[k * 10 + j];
    }
#pragma unroll
    for (int j = 0; j < 10; ++j)
        for (int off = 1; off < 64; off <<= 1) logit[j] += __shfl_xor(logit[j], off, 64);
    if (lane == 0) {
        float m = -1e30f;
#pragma unroll
        for (int j = 0; j < 10; ++j) { logit[j] += b[j]; m = fmaxf(m, logit[j]); }
        float sum = 0.f;
#pragma unroll
        for (int j = 0; j < 10; ++j) sum += expf(logit[j] - m);
        float lse = m + logf(sum);
#pragma unroll
        for (int j = 0; j < 10; ++j) out[r * 10 + j] = logit[j] - lse;
    }
}

extern "C" void kernel_launch(void* const* d_in, const int* in_sizes, int n_in,
                              void* d_out, int out_size, void* d_ws, size_t ws_size,
                              hipStream_t stream) {
    const float* x      = (const float*)d_in[0];
    const int*   ei     = (const int*)d_in[1];
    const int*   batch  = (const int*)d_in[2];
    const float* w_feat = (const float*)d_in[3];
    const float* bnf_g  = (const float*)d_in[4];
    const float* bnf_b  = (const float*)d_in[5];
    const float* bnc_g  = (const float*)d_in[6];
    const float* bnc_b  = (const float*)d_in[7];
    const float* gat_w  = (const float*)d_in[8];
    const float* gat_as = (const float*)d_in[9];
    const float* gat_ad = (const float*)d_in[10];
    const float* gat_b  = (const float*)d_in[11];
    const float* bnfc_g = (const float*)d_in[12];
    const float* bnfc_b = (const float*)d_in[13];
    const float* lin_w  = (const float*)d_in[14];
    const float* lin_b  = (const float*)d_in[15];
    const float* bnh_g  = (const float*)d_in[16];
    const float* bnh_b  = (const float*)d_in[17];
    const float* cls_w  = (const float*)d_in[18];
    const float* cls_b  = (const float*)d_in[19];
    float* out = (float*)d_out;

    char* ws = (char*)d_ws;
    size_t off = 0;
    auto alloc = [&](size_t bytes) -> void* {
        void* p = ws + off;
        off = (off + bytes + 255) & ~(size_t)255;
        return p;
    };
    _Float16* xh   = (_Float16*)alloc((size_t)N_NODES * 128 * 2);
    _Float16* h    = (_Float16*)alloc((size_t)N_NODES * 128 * 2);
    _Float16* hp   = (_Float16*)alloc((size_t)N_NODES * 128 * 2);
    float*    als  = (float*)alloc((size_t)N_NODES * 4 * 4);
    float*    ald  = (float*)alloc((size_t)N_NODES * 4 * 4);
    int*      curs = (int*)alloc((size_t)N_NODES * 4);
    unsigned short* col = (unsigned short*)alloc((size_t)N_NODES * DMAX * 2);
    float*    SB   = (float*)alloc(SB_TOT * 4);
    float*    g    = (float*)alloc(NGRAPHS * 128 * 4);
    float*    g2   = (float*)alloc(NGRAPHS * 128 * 4);

    const int* esrc = ei;
    const int* edst = ei + N_EDGES;
    const float fin = 1.f / N_NODES;

    // ---- init (zero SB incl BOTH conv stat buffers; self-loop slot 0; cursor=1) ----
    init_kernel<<<divup(N_NODES, 256), 256, 0, stream>>>(SB, curs, col, N_NODES);

    // ---- cast + feat stats ----
    cast_stats<<<256, 256, 0, stream>>>(x, xh, N_NODES, SB + SB_X);

    // ---- feat gemm: inline fold from SB_X (nsl=1); stats of h -> CONV0;
    //      carries scatter chunks 0..HALF0-1 ----
    gemm_mfma<<<GEMM_BLOCKS + HALF0 * 8, 512, 0, stream>>>(
        xh, w_feat, bnf_g, bnf_b, SB + SB_X, 1, fin,
        h, N_NODES, 1,
        nullptr, nullptr, nullptr, nullptr,
        SB + SB_CONV0, nullptr, nullptr,
        esrc, edst, curs, col, N_EDGES, 0);

    // ---- 3 GAT conv layers; stats double-buffer CONV0/CONV1:
    // conv0 fold<-CONV0 (zero nothing: CONV1 init-zeroed), colstats0 -> CONV1
    // conv1 fold<-CONV1, zeroes CONV0,                      colstats1 -> CONV0
    // conv2 fold<-CONV0, zeroes g (pool target)
    for (int i = 0; i < NCONV; ++i) {
        const float* foldsrc = (i == 1) ? SB + SB_CONV1 : SB + SB_CONV0;
        float* sz = (i == 1) ? SB + SB_CONV0 : nullptr;
        float* gz = (i == 2) ? g : nullptr;
        int nblk = GEMM_BLOCKS + ((i == 0) ? (NCHUNKS - HALF0) * 8 : 0);
        gemm_mfma<<<nblk, 512, 0, stream>>>(
            h, gat_w + 16384 * i, bnc_g + 128 * i, bnc_b + 128 * i, foldsrc, 8, fin,
            hp, N_NODES, 0,
            gat_as + 128 * i, gat_ad + 128 * i,
            als, ald, nullptr, sz, gz,
            (i == 0) ? esrc : nullptr, (i == 0) ? edst : nullptr,
            (i == 0) ? curs : nullptr, (i == 0) ? col : nullptr,
            (i == 0) ? N_EDGES : 0, HALF0);
        gat_aggregate<<<N_NODES / 4, 256, 0, stream>>>(hp, als, ald, curs, col,
                                                       gat_b + 128 * i, h, N_NODES);
        if (i < NCONV - 1)
            colstats_h<<<256, 256, 0, stream>>>(h, N_NODES,
                                                (i == 0) ? SB + SB_CONV1 : SB + SB_CONV0);
    }

    // ---- pool + MLP head (BN stats in-kernel; epilogue fills SB_H2 for final) ----
    pool_kernel<<<divup(N_NODES, 32), 128, 0, stream>>>(h, batch, g, N_NODES, 32);
    gemm128_bn<<<divup(NGRAPHS, 32), 256, 0, stream>>>(g, lin_w, lin_b, 1.f / NGRAPHS,
                                                       bnfc_g, bnfc_b, g2, SB + SB_H2, NGRAPHS);
    final_kernel<<<NGRAPHS, 64, 0, stream>>>(g2, SB + SB_H2, 1.f / NGRAPHS, bnh_g, bnh_b,
                                             cls_w, cls_b, out, NGRAPHS);
}